// Round 5
// baseline (484.373 us; speedup 1.0000x reference)
//
#include <hip/hip_runtime.h>
#include <hip/hip_cooperative_groups.h>
#include <math.h>

namespace cg = cooperative_groups;

#define NB 64
#define LIN 4001
#define LC 998
#define ND 1000
#define EPSBN 1e-5f

#define CK 104
#define NCH_LIN 10       // ceil(998/104)  -> last jc = 62
#define NCH_OUT 10       // ceil(1000/104) -> last jc = 64
#define T_LIN 480        // 16 d-tiles * 3 which * 10 chunks
#define T_OUT 160        // 16 e-tiles * 10 chunks
#define GRID 512

// ws float offsets
#define OFF_CONVT 0u         // 3*998*64      = 191616
#define OFF_PP    191616u    // 10*3*16*4096  = 1966080
#define OFF_Q     2157696u   // 64*1000       = 64000
#define OFF_KV    2221696u   // 64*2048       = 131072
#define OFF_CF    2352768u   // 1000*64       = 64000  (cfT[i][b])
#define OFF_OP    2416768u   // 10*16*4096    = 655360
// end = 3072128 floats = 12.3 MB

struct Params {
    const float *x, *g, *be, *mu, *va;
    const float *cwq, *cbq, *lwq, *lbq;
    const float *cwk, *cbk, *lwk, *lbk;
    const float *cwv, *cbv, *lwv, *lbv;
    const float *ipw, *ipb, *opw, *opb, *W, *outb;
    float *convT, *Pp, *qg, *kvg, *cfT, *Op, *out;
};

// GEMM microtile body: 64b x 64d x jc(<=104). lds needs 13376 floats.
__device__ __forceinline__ void gemm_tile(
    const float* __restrict__ Asrc,   // [jc][64] chunk, b-contiguous
    const float* __restrict__ Brow,   // weight base, row stride ldB
    int ldB, int dgb, int j0, int jc,
    float* __restrict__ Pt,           // output tile [64 b][64 d]
    float* lds)
{
    float* ldsC = lds;                // [104][64] = 6656
    float* ldsW = lds + 6656;         // [64][105] = 6720
    int tid  = threadIdx.x;
    int lane = tid & 63;
    int w    = tid >> 6;
    int b0   = (lane & 7) << 3;
    int d0   = (lane >> 3) << 3;

    {   // stage A chunk via float4 (fully coalesced)
        const float4* src = (const float4*)Asrc;
        float4* dst = (float4*)ldsC;
        for (int t = tid; t < jc * 16; t += 256) dst[t] = src[t];
    }
    // stage B tile via float2: 64 rows x 52 f2
    for (int idx = tid; idx < 3328; idx += 256) {
        int dd = idx / 52, j2 = idx % 52;
        int dg = dgb + dd;
        float2 v = make_float2(0.f, 0.f);
        if (dg < ND && 2 * j2 < jc)
            v = *(const float2*)(Brow + (size_t)dg * ldB + j0 + 2 * j2);
        ldsW[dd * 105 + 2 * j2]     = v.x;
        ldsW[dd * 105 + 2 * j2 + 1] = v.y;
    }
    __syncthreads();

    float acc[8][8];
#pragma unroll
    for (int i = 0; i < 8; ++i)
#pragma unroll
        for (int jx = 0; jx < 8; ++jx) acc[i][jx] = 0.f;

    int js = (jc * w) >> 2;
    int je = (jc * (w + 1)) >> 2;
    for (int jj = js; jj < je; ++jj) {
        float4 c0 = *(const float4*)(ldsC + jj * 64 + b0);
        float4 c1 = *(const float4*)(ldsC + jj * 64 + b0 + 4);
        float cv[8] = {c0.x, c0.y, c0.z, c0.w, c1.x, c1.y, c1.z, c1.w};
        float wv[8];
#pragma unroll
        for (int r = 0; r < 8; ++r) wv[r] = ldsW[(d0 + r) * 105 + jj];
#pragma unroll
        for (int i = 0; i < 8; ++i)
#pragma unroll
            for (int jx = 0; jx < 8; ++jx)
                acc[i][jx] = fmaf(cv[i], wv[jx], acc[i][jx]);
    }
    __syncthreads();   // done with staged data; reuse LDS for reduce

    for (int p = 0; p < 2; ++p) {
        float* red = lds + w * 2304;   // per-wave [64][36]
#pragma unroll
        for (int i = 0; i < 8; ++i)
            *(float4*)(red + (b0 + i) * 36 + (d0 >> 1)) =
                make_float4(acc[i][4*p], acc[i][4*p+1], acc[i][4*p+2], acc[i][4*p+3]);
        __syncthreads();
        for (int t = tid; t < 512; t += 256) {
            int bb = t >> 3, gg = t & 7;
            int o = bb * 36 + 4 * gg;
            float4 a0 = *(const float4*)(lds + o);
            float4 a1 = *(const float4*)(lds + 2304 + o);
            float4 a2 = *(const float4*)(lds + 4608 + o);
            float4 a3 = *(const float4*)(lds + 6912 + o);
            float4 s;
            s.x = a0.x + a1.x + a2.x + a3.x;
            s.y = a0.y + a1.y + a2.y + a3.y;
            s.z = a0.z + a1.z + a2.z + a3.z;
            s.w = a0.w + a1.w + a2.w + a3.w;
            *(float4*)(Pt + bb * 64 + 8 * gg + 4 * p) = s;
        }
        __syncthreads();
    }
}

__global__ __launch_bounds__(256, 2) void k_all(Params p)
{
    __shared__ float lds[13376];      // 53504 B -> 3 blocks/CU
    cg::grid_group grid = cg::this_grid();
    const int tid = threadIdx.x;
    const int bid = blockIdx.x;
    const int gsz = GRID * 256;
    const int gtid = bid * 256 + tid;

    // ---------------- P1: BatchNorm + strided conv -> convT[w][j][b] --------
    {
        int idx = gtid;
        if (idx < LC * NB) {
            int j = idx % LC, b = idx / LC;
            const float* xb = p.x + (size_t)b * LIN + 4 * j;
            float aq = 0.f, ak = 0.f, av = 0.f;
#pragma unroll
            for (int t = 0; t < 10; ++t) {
                int i = 4 * j + t;
                float s  = p.g[i] * rsqrtf(p.va[i] + EPSBN);
                float xn = (xb[t] - p.mu[i]) * s + p.be[i];
                aq = fmaf(xn, p.cwq[t], aq);
                ak = fmaf(xn, p.cwk[t], ak);
                av = fmaf(xn, p.cwv[t], av);
            }
            p.convT[((size_t)0 * LC + j) * 64 + b] = aq + p.cbq[0];
            p.convT[((size_t)1 * LC + j) * 64 + b] = ak + p.cbk[0];
            p.convT[((size_t)2 * LC + j) * 64 + b] = av + p.cbv[0];
        }
    }
    grid.sync();

    // ---------------- P2: QKV GEMM partials -> Pp (480 tiles, 1 round) ------
    if (bid < T_LIN) {
        int t = bid;
        int dx = t & 15;
        int which = (t >> 4) % 3;
        int chunk = t / 48;
        int j0 = chunk * CK;
        int jc = (LC - j0 < CK) ? (LC - j0) : CK;
        const float* lw = (which == 0) ? p.lwq : ((which == 1) ? p.lwk : p.lwv);
        const float* Asrc = p.convT + ((size_t)which * LC + j0) * 64;
        float* Pt = p.Pp + (((size_t)chunk * 3 + which) * 16 + dx) * 4096;
        gemm_tile(Asrc, lw, LC, dx * 64, j0, jc, Pt, lds);
    }
    grid.sync();

    // ---------------- P3: reduce chunks + bias/ReLU/in_proj -> qg, kvg ------
    {
        int idx = gtid;
        if (idx < NB * ND) {
            int i = idx % ND, b = idx / ND;
            int it = i >> 6, il = i & 63;
            size_t base = ((size_t)it) * 4096 + (b << 6) + il;
            float s0 = 0.f, s1 = 0.f, s2 = 0.f;
            for (int c = 0; c < NCH_LIN; ++c) {
                size_t o = ((size_t)c * 3 * 16) * 4096 + base;
                s0 += p.Pp[o];
                s1 += p.Pp[o + 16 * 4096];
                s2 += p.Pp[o + 32 * 4096];
            }
            const float LOG2E = 1.4426950408889634f;
            float yq = fmaxf(s0 + p.lbq[i], 0.f) * p.ipw[0] + p.ipb[0];
            float yk = fmaxf(s1 + p.lbk[i], 0.f) * p.ipw[1] + p.ipb[1];
            float yv = fmaxf(s2 + p.lbv[i], 0.f) * p.ipw[2] + p.ipb[2];
            p.qg[(size_t)b * ND + i] = yq;
            p.kvg[(size_t)b * 2048 + 2 * i]     = yk * LOG2E;
            p.kvg[(size_t)b * 2048 + 2 * i + 1] = yv;
        }
    }
    grid.sync();

    // ---------------- P4: attention (512 items = 8 i-tiles x 64 b) ----------
    {
        float* skv  = lds;           // 2000
        float* sql  = lds + 2000;    // 128
        float* sd   = lds + 2128;    // 512
        float* sn   = lds + 2640;    // 512
        float* rmax = lds + 3152;    // 4
        float* rmin = lds + 3156;    // 4
        int t  = bid;
        int i0 = (t & 7) * 128;
        int b  = t >> 3;
        int w    = tid >> 6;
        int lane = tid & 63;

        {   // stage kv[b] (8 KB), k pre-scaled by log2e
            const float4* src = (const float4*)(p.kvg + (size_t)b * 2048);
            float4* dst = (float4*)skv;
            for (int tt = tid; tt < 500; tt += 256) dst[tt] = src[tt];
        }
        if (tid < 128) {
            int i = i0 + tid;
            sql[tid] = (i < ND) ? p.qg[(size_t)b * ND + i] : 0.f;
        }
        __syncthreads();

        float km = -INFINITY, kn = INFINITY;
        for (int j = tid; j < ND; j += 256) {
            float f = skv[2 * j];
            km = fmaxf(km, f);
            kn = fminf(kn, f);
        }
#pragma unroll
        for (int off = 1; off < 64; off <<= 1) {
            km = fmaxf(km, __shfl_xor(km, off));
            kn = fminf(kn, __shfl_xor(kn, off));
        }
        if (lane == 0) { rmax[w] = km; rmin[w] = kn; }
        __syncthreads();
        km = fmaxf(fmaxf(rmax[0], rmax[1]), fmaxf(rmax[2], rmax[3]));
        kn = fminf(fminf(rmin[0], rmin[1]), fminf(rmin[2], rmin[3]));

        float q0 = sql[lane];
        float q1 = sql[64 + lane];
        float m0 = (q0 >= 0.f) ? q0 * km : q0 * kn;
        float m1 = (q1 >= 0.f) ? q1 * km : q1 * kn;
        const float2* kv2 = (const float2*)skv;
        int jb = w * 250;
        float d0a = 0.f, n0a = 0.f, d1a = 0.f, n1a = 0.f;
#pragma unroll 2
        for (int jl = 0; jl < 250; ++jl) {
            float2 f = kv2[jb + jl];
            float e0 = exp2f(fmaf(q0, f.x, -m0));
            float e1 = exp2f(fmaf(q1, f.x, -m1));
            d0a += e0; n0a = fmaf(e0, f.y, n0a);
            d1a += e1; n1a = fmaf(e1, f.y, n1a);
        }
        sd[w * 128 + lane]      = d0a;
        sd[w * 128 + 64 + lane] = d1a;
        sn[w * 128 + lane]      = n0a;
        sn[w * 128 + 64 + lane] = n1a;
        __syncthreads();

        if (tid < 128) {
            int i = i0 + tid;
            if (i < ND) {
                float dt = sd[tid] + sd[128 + tid] + sd[256 + tid] + sd[384 + tid];
                float nt = sn[tid] + sn[128 + tid] + sn[256 + tid] + sn[384 + tid];
                p.cfT[(size_t)i * 64 + b] = (nt / dt) * p.opw[0] + p.opb[0];
            }
        }
        __syncthreads();   // protect lds before P5 reuse (grid.sync follows anyway)
    }
    grid.sync();

    // ---------------- P5: out GEMM partials -> Op (160 tiles) ---------------
    if (bid < T_OUT) {
        int t = bid;
        int dx = t & 15;
        int chunk = t >> 4;
        int j0 = chunk * CK;
        int jc = (ND - j0 < CK) ? (ND - j0) : CK;
        const float* Asrc = p.cfT + (size_t)j0 * 64;
        float* Pt = p.Op + ((size_t)chunk * 16 + dx) * 4096;
        gemm_tile(Asrc, p.W, ND, dx * 64, j0, jc, Pt, lds);
    }
    grid.sync();

    // ---------------- P6: reduce Op chunks + bias -> out --------------------
    {
        int idx = gtid;
        if (idx < NB * ND) {
            int e = idx % ND, b = idx / ND;
            float s = p.outb[e];
            size_t cell = ((size_t)(e >> 6)) * 4096 + (b << 6) + (e & 63);
            for (int c = 0; c < NCH_OUT; ++c)
                s += p.Op[(size_t)c * 16 * 4096 + cell];
            p.out[(size_t)b * ND + e] = s;
        }
    }
}

extern "C" void kernel_launch(void* const* d_in, const int* in_sizes, int n_in,
                              void* d_out, int out_size, void* d_ws, size_t ws_size,
                              hipStream_t stream)
{
    float* ws = (float*)d_ws;
    Params p;
    p.x    = (const float*)d_in[0];
    p.g    = (const float*)d_in[1];
    p.be   = (const float*)d_in[2];
    p.mu   = (const float*)d_in[3];
    p.va   = (const float*)d_in[4];
    p.cwq  = (const float*)d_in[5];
    p.cbq  = (const float*)d_in[6];
    p.lwq  = (const float*)d_in[7];
    p.lbq  = (const float*)d_in[8];
    p.cwk  = (const float*)d_in[9];
    p.cbk  = (const float*)d_in[10];
    p.lwk  = (const float*)d_in[11];
    p.lbk  = (const float*)d_in[12];
    p.cwv  = (const float*)d_in[13];
    p.cbv  = (const float*)d_in[14];
    p.lwv  = (const float*)d_in[15];
    p.lbv  = (const float*)d_in[16];
    p.ipw  = (const float*)d_in[17];
    p.ipb  = (const float*)d_in[18];
    p.opw  = (const float*)d_in[19];
    p.opb  = (const float*)d_in[20];
    p.W    = (const float*)d_in[21];
    p.outb = (const float*)d_in[22];
    p.convT = ws + OFF_CONVT;
    p.Pp    = ws + OFF_PP;
    p.qg    = ws + OFF_Q;
    p.kvg   = ws + OFF_KV;
    p.cfT   = ws + OFF_CF;
    p.Op    = ws + OFF_OP;
    p.out   = (float*)d_out;

    void* args[] = {&p};
    hipLaunchCooperativeKernel((void*)k_all, dim3(GRID), dim3(256),
                               args, 0, stream);
}

// Round 6
// 173.503 us; speedup vs baseline: 2.7917x; 2.7917x over previous
//
#include <hip/hip_runtime.h>
#include <math.h>

#define NB 64
#define LIN 4001
#define LC 998
#define ND 1000
#define EPSBN 1e-5f

#define KP 1024          // padded K for convT / cfT
#define CKL 128          // k_lin chunk (8 chunks over KP)
#define NCH_LIN 8
#define CKO 64           // k_out chunk (16 chunks over KP)
#define NCH_OUT 16

// ws float offsets
#define OFF_CONVT 0u         // 3*1024*64     = 196608
#define OFF_PP    196608u    // 8*3*16*4096   = 1572864
#define OFF_Q     1769472u   // 64*1000       = 64000
#define OFF_KV    1833472u   // 64*2048       = 131072
#define OFF_CF    1964544u   // 1024*64       = 65536  (cfT[i][b], zero-padded)
#define OFF_OP    2030080u   // 16*16*4096    = 1048576
// end = 3078656 floats = 12.3 MB

// ---------------- K1: fused BatchNorm + strided conv -> convT[w][j][b] ------
// grid (4,64): j covers 0..1023 exactly; j>=998 zero-filled (K padding).
__global__ __launch_bounds__(256) void k_bnconv(
    const float* __restrict__ x,
    const float* __restrict__ g, const float* __restrict__ be,
    const float* __restrict__ mu, const float* __restrict__ va,
    const float* __restrict__ cwq, const float* __restrict__ cbq,
    const float* __restrict__ cwk, const float* __restrict__ cbk,
    const float* __restrict__ cwv, const float* __restrict__ cbv,
    float* __restrict__ convT)
{
    int j = blockIdx.x * 256 + threadIdx.x;
    int b = blockIdx.y;
    float aq = 0.f, ak = 0.f, av = 0.f;
    if (j < LC) {
        const float* xb = x + (size_t)b * LIN + 4 * j;
#pragma unroll
        for (int t = 0; t < 10; ++t) {
            int i = 4 * j + t;
            float s  = g[i] * rsqrtf(va[i] + EPSBN);
            float xn = (xb[t] - mu[i]) * s + be[i];
            aq = fmaf(xn, cwq[t], aq);
            ak = fmaf(xn, cwk[t], ak);
            av = fmaf(xn, cwv[t], av);
        }
        aq += cbq[0]; ak += cbk[0]; av += cbv[0];
    }
    convT[((size_t)0 * KP + j) * 64 + b] = aq;
    convT[((size_t)1 * KP + j) * 64 + b] = ak;
    convT[((size_t)2 * KP + j) * 64 + b] = av;
}

// ---- cross-wave reduce of acc[8][8] -> Pt[64b][64d] (two f4 passes) --------
__device__ __forceinline__ void reduce_store(
    float acc[8][8], float* lds, float* __restrict__ Pt,
    int tid, int w, int b0, int d0)
{
    for (int p = 0; p < 2; ++p) {
        float* red = lds + w * 2304;   // per-wave [64][36]
#pragma unroll
        for (int i = 0; i < 8; ++i)
            *(float4*)(red + (b0 + i) * 36 + (d0 >> 1)) =
                make_float4(acc[i][4*p], acc[i][4*p+1], acc[i][4*p+2], acc[i][4*p+3]);
        __syncthreads();
        for (int t = tid; t < 512; t += 256) {
            int bb = t >> 3, gg = t & 7;
            int o = bb * 36 + 4 * gg;
            float4 a0 = *(const float4*)(lds + o);
            float4 a1 = *(const float4*)(lds + 2304 + o);
            float4 a2 = *(const float4*)(lds + 4608 + o);
            float4 a3 = *(const float4*)(lds + 6912 + o);
            float4 s;
            s.x = a0.x + a1.x + a2.x + a3.x;
            s.y = a0.y + a1.y + a2.y + a3.y;
            s.z = a0.z + a1.z + a2.z + a3.z;
            s.w = a0.w + a1.w + a2.w + a3.w;
            *(float4*)(Pt + bb * 64 + 8 * gg + 4 * p) = s;
        }
        __syncthreads();
    }
}

// ---- streaming GEMM body: C from global (broadcast f4), W via f2 pairs -----
// Cb: [CK][64] (b-contig, aligned); Wb: thread's row base (dg0 = dgb+d0);
// jls..jls+nj: this wave's j range (multiple of 2); jmax = valid K limit.
__device__ __forceinline__ void stream_mm(
    float acc[8][8], const float* __restrict__ Cb,
    const float* __restrict__ Wb, int ldB,
    int j0, int jls, int nj, int jmax)
{
    for (int g2 = 0; g2 < (nj >> 1); ++g2) {
        int jl = jls + 2 * g2;
        int jg = j0 + jl;
        float2 w2[8];
        if (jg + 2 <= jmax) {
#pragma unroll
            for (int r = 0; r < 8; ++r)
                w2[r] = *(const float2*)(Wb + (size_t)r * ldB + jl);
        } else {
#pragma unroll
            for (int r = 0; r < 8; ++r) {
                w2[r].x = (jg     < jmax) ? Wb[(size_t)r * ldB + jl]     : 0.f;
                w2[r].y = (jg + 1 < jmax) ? Wb[(size_t)r * ldB + jl + 1] : 0.f;
            }
        }
#pragma unroll
        for (int u = 0; u < 2; ++u) {
            const float* cp = Cb + (size_t)(jl + u) * 64;
            float4 c0 = *(const float4*)(cp);
            float4 c1 = *(const float4*)(cp + 4);
            float cv[8] = {c0.x, c0.y, c0.z, c0.w, c1.x, c1.y, c1.z, c1.w};
#pragma unroll
            for (int i = 0; i < 8; ++i) {
#pragma unroll
                for (int jx = 0; jx < 8; ++jx) {
                    float wv = u ? w2[jx].y : w2[jx].x;
                    acc[i][jx] = fmaf(cv[i], wv, acc[i][jx]);
                }
            }
        }
    }
}

// ---------------- K2: QKV GEMM partials -> Pp (no LDS staging) --------------
// grid (16 d-tiles, 3 which, 8 chunks of 128 over padded K)
__global__ __launch_bounds__(256, 3) void k_lin(
    const float* __restrict__ convT,
    const float* __restrict__ lwq, const float* __restrict__ lwk,
    const float* __restrict__ lwv,
    float* __restrict__ Pp)
{
    __shared__ float lds[9216];
    int tid  = threadIdx.x;
    int lane = tid & 63;
    int w    = tid >> 6;
    int b0   = (lane & 7) << 3;
    int d0   = (lane >> 3) << 3;
    int dgb   = blockIdx.x * 64;
    int which = blockIdx.y;
    int chunk = blockIdx.z;
    int j0 = chunk * CKL;
    const float* lw = (which == 0) ? lwq : ((which == 1) ? lwk : lwv);
    const float* Cb = convT + ((size_t)which * KP + j0) * 64 + b0;
    const float* Wb = lw + (size_t)(dgb + d0) * LC + j0;

    float acc[8][8];
#pragma unroll
    for (int i = 0; i < 8; ++i)
#pragma unroll
        for (int jx = 0; jx < 8; ++jx) acc[i][jx] = 0.f;

    stream_mm(acc, Cb, Wb, LC, j0, w * 32, 32, LC);

    __syncthreads();
    float* Pt = Pp + (((size_t)chunk * 3 + which) * 16 + blockIdx.x) * 4096;
    reduce_store(acc, lds, Pt, tid, w, b0, d0);
}

// ---------------- K3: reduce chunks + bias/ReLU/in_proj -> q, kv ------------
__global__ __launch_bounds__(256) void k_act(
    const float* __restrict__ Pp,
    const float* __restrict__ lbq, const float* __restrict__ lbk,
    const float* __restrict__ lbv,
    const float* __restrict__ ipw, const float* __restrict__ ipb,
    float* __restrict__ q, float* __restrict__ kv)
{
    int i = blockIdx.x * 256 + threadIdx.x;
    int b = blockIdx.y;
    if (i >= ND) return;
    int it = i >> 6, il = i & 63;
    float s0 = 0.f, s1 = 0.f, s2 = 0.f;
    for (int c = 0; c < NCH_LIN; ++c) {
        size_t base = (((size_t)c * 3) * 16 + it) * 4096 + (il | (b << 6));
        s0 += Pp[base];
        s1 += Pp[base + 16 * 4096];
        s2 += Pp[base + 32 * 4096];
    }
    const float LOG2E = 1.4426950408889634f;
    float yq = fmaxf(s0 + lbq[i], 0.f) * ipw[0] + ipb[0];
    float yk = fmaxf(s1 + lbk[i], 0.f) * ipw[1] + ipb[1];
    float yv = fmaxf(s2 + lbv[i], 0.f) * ipw[2] + ipb[2];
    q[(size_t)b * ND + i] = yq;
    kv[(size_t)b * 2048 + 2 * i]     = yk * LOG2E;   // pre-scaled for exp2
    kv[(size_t)b * 2048 + 2 * i + 1] = yv;
}

// ---------------- K4: attention, 4-way wave K-split, writes cfT[i][b] -------
// grid (16 i-tiles of 64, 64 b) covers i<1024; i>=1000 writes 0 (K pad).
__global__ __launch_bounds__(256) void k_attn(
    const float* __restrict__ q, const float* __restrict__ kv,
    const float* __restrict__ opw, const float* __restrict__ opb,
    float* __restrict__ cfT)
{
    __shared__ float ldsKV[2048];
    __shared__ float sden[256];
    __shared__ float snum[256];
    __shared__ float rmax[4];
    __shared__ float rmin[4];
    int tid = threadIdx.x;
    int b   = blockIdx.y;
    int w   = tid >> 6;
    int ii  = tid & 63;
    int i   = blockIdx.x * 64 + ii;

    {   // stage kv[b] (8 KB; k pre-scaled by log2e)
        const float4* src = (const float4*)(kv + (size_t)b * 2048);
        float4* dst = (float4*)ldsKV;
        for (int t = tid; t < 500; t += 256) dst[t] = src[t];
    }
    __syncthreads();

    const float2* kv2 = (const float2*)ldsKV;
    float km = -INFINITY, kn = INFINITY;
    for (int idx = tid; idx < ND; idx += 256) {
        float f = ldsKV[2 * idx];
        km = fmaxf(km, f);
        kn = fminf(kn, f);
    }
#pragma unroll
    for (int off = 1; off < 64; off <<= 1) {
        km = fmaxf(km, __shfl_xor(km, off));
        kn = fminf(kn, __shfl_xor(kn, off));
    }
    if (ii == 0) { rmax[w] = km; rmin[w] = kn; }
    __syncthreads();
    km = fmaxf(fmaxf(rmax[0], rmax[1]), fmaxf(rmax[2], rmax[3]));
    kn = fminf(fminf(rmin[0], rmin[1]), fminf(rmin[2], rmin[3]));

    float qi = (i < ND) ? q[(size_t)b * ND + i] : 0.f;
    float m  = (qi >= 0.f) ? qi * km : qi * kn;

    int jb = w * 250;
    float den = 0.f, num = 0.f;
#pragma unroll 2
    for (int jl = 0; jl < 250; ++jl) {
        float2 f = kv2[jb + jl];
        float e  = exp2f(fmaf(qi, f.x, -m));
        den += e;
        num = fmaf(e, f.y, num);
    }
    sden[tid] = den;
    snum[tid] = num;
    __syncthreads();
    if (w == 0) {
        float dt = sden[ii] + sden[64 + ii] + sden[128 + ii] + sden[192 + ii];
        float nt = snum[ii] + snum[64 + ii] + snum[128 + ii] + snum[192 + ii];
        float v  = (i < ND) ? (nt / dt) * opw[0] + opb[0] : 0.f;
        cfT[(size_t)i * 64 + b] = v;
    }
}

// ---------------- K5: out GEMM partials -> Op (no LDS staging) --------------
// grid (16 e-tiles, 16 chunks of 64 over padded K=1024)
__global__ __launch_bounds__(256, 3) void k_out(
    const float* __restrict__ cfT, const float* __restrict__ W,
    float* __restrict__ Op)
{
    __shared__ float lds[9216];
    int tid  = threadIdx.x;
    int lane = tid & 63;
    int w    = tid >> 6;
    int b0   = (lane & 7) << 3;
    int d0   = (lane >> 3) << 3;
    int egb   = blockIdx.x * 64;
    int chunk = blockIdx.y;
    int j0 = chunk * CKO;
    const float* Cb = cfT + (size_t)j0 * 64 + b0;
    const float* Wb = W + (size_t)(egb + d0) * ND + j0;

    float acc[8][8];
#pragma unroll
    for (int i = 0; i < 8; ++i)
#pragma unroll
        for (int jx = 0; jx < 8; ++jx) acc[i][jx] = 0.f;

    stream_mm(acc, Cb, Wb, ND, j0, w * 16, 16, ND);

    __syncthreads();
    float* Pt = Op + ((size_t)chunk * 16 + blockIdx.x) * 4096;
    reduce_store(acc, lds, Pt, tid, w, b0, d0);
}

// ---------------- K6: reduce Op chunks + bias -> out ------------------------
__global__ __launch_bounds__(256) void k_fin(
    const float* __restrict__ Op, const float* __restrict__ outb,
    float* __restrict__ out)
{
    int e = blockIdx.x * 256 + threadIdx.x;
    int b = blockIdx.y;
    if (e >= ND) return;
    float s = outb[e];
    size_t cell = ((size_t)(e >> 6)) * 4096 + (b << 6) + (e & 63);
    for (int c = 0; c < NCH_OUT; ++c)
        s += Op[(size_t)c * 16 * 4096 + cell];
    out[(size_t)b * ND + e] = s;
}

extern "C" void kernel_launch(void* const* d_in, const int* in_sizes, int n_in,
                              void* d_out, int out_size, void* d_ws, size_t ws_size,
                              hipStream_t stream)
{
    const float* x    = (const float*)d_in[0];
    const float* g    = (const float*)d_in[1];
    const float* be   = (const float*)d_in[2];
    const float* mu   = (const float*)d_in[3];
    const float* va   = (const float*)d_in[4];
    const float* cwq  = (const float*)d_in[5];
    const float* cbq  = (const float*)d_in[6];
    const float* lwq  = (const float*)d_in[7];
    const float* lbq  = (const float*)d_in[8];
    const float* cwk  = (const float*)d_in[9];
    const float* cbk  = (const float*)d_in[10];
    const float* lwk  = (const float*)d_in[11];
    const float* lbk  = (const float*)d_in[12];
    const float* cwv  = (const float*)d_in[13];
    const float* cbv  = (const float*)d_in[14];
    const float* lwv  = (const float*)d_in[15];
    const float* lbv  = (const float*)d_in[16];
    const float* ipw  = (const float*)d_in[17];
    const float* ipb  = (const float*)d_in[18];
    const float* opw  = (const float*)d_in[19];
    const float* opb  = (const float*)d_in[20];
    const float* W    = (const float*)d_in[21];
    const float* outb = (const float*)d_in[22];

    float* ws    = (float*)d_ws;
    float* convT = ws + OFF_CONVT;
    float* Pp    = ws + OFF_PP;
    float* q     = ws + OFF_Q;
    float* kv    = ws + OFF_KV;
    float* cfT   = ws + OFF_CF;
    float* Op    = ws + OFF_OP;
    float* out   = (float*)d_out;

    k_bnconv<<<dim3(4, 64), 256, 0, stream>>>(x, g, be, mu, va,
                                              cwq, cbq, cwk, cbk, cwv, cbv, convT);
    k_lin  <<<dim3(16, 3, NCH_LIN), 256, 0, stream>>>(convT, lwq, lwk, lwv, Pp);
    k_act  <<<dim3(4, 64), 256, 0, stream>>>(Pp, lbq, lbk, lbv, ipw, ipb, q, kv);
    k_attn <<<dim3(16, 64), 256, 0, stream>>>(q, kv, opw, opb, cfT);
    k_out  <<<dim3(16, NCH_OUT), 256, 0, stream>>>(cfT, W, Op);
    k_fin  <<<dim3(4, 64), 256, 0, stream>>>(Op, outb, out);
}

// Round 7
// 170.455 us; speedup vs baseline: 2.8416x; 1.0179x over previous
//
#include <hip/hip_runtime.h>
#include <math.h>

#define NB 64
#define LIN 4001
#define LC 998
#define ND 1000
#define EPSBN 1e-5f

#define CK 96            // K-chunk for k_lin & k_out
#define NCH_LIN 11       // ceil(998/96)
#define NCH_OUT 11       // ceil(1000/96)

// ws float offsets
#define OFF_CONVT 0u        // 3*998*64      = 191616
#define OFF_PP    191616u   // 11*3*16*4096  = 2162688
#define OFF_Q     2354304u  // 64*1000       = 64000
#define OFF_KV    2418304u  // 64*2048       = 131072
#define OFF_CF    2549376u  // 1000*64       = 64000   (cfT[i][b])
#define OFF_OP    2613376u  // 11*16*4096    = 720896
// end = 3334272 floats = 13.3 MB

// ---------------- K1: fused BatchNorm + strided conv -> convT[w][j][b] ------
__global__ __launch_bounds__(256) void k_bnconv(
    const float* __restrict__ x,
    const float* __restrict__ g, const float* __restrict__ be,
    const float* __restrict__ mu, const float* __restrict__ va,
    const float* __restrict__ cwq, const float* __restrict__ cbq,
    const float* __restrict__ cwk, const float* __restrict__ cbk,
    const float* __restrict__ cwv, const float* __restrict__ cbv,
    float* __restrict__ convT)
{
    int j = blockIdx.x * 256 + threadIdx.x;
    int b = blockIdx.y;
    if (j >= LC) return;
    const float* xb = x + (size_t)b * LIN + 4 * j;
    float aq = 0.f, ak = 0.f, av = 0.f;
#pragma unroll
    for (int t = 0; t < 10; ++t) {
        int i = 4 * j + t;
        float s  = g[i] * rsqrtf(va[i] + EPSBN);
        float xn = (xb[t] - mu[i]) * s + be[i];
        aq = fmaf(xn, cwq[t], aq);
        ak = fmaf(xn, cwk[t], ak);
        av = fmaf(xn, cwv[t], av);
    }
    convT[((size_t)0 * LC + j) * 64 + b] = aq + cbq[0];
    convT[((size_t)1 * LC + j) * 64 + b] = ak + cbk[0];
    convT[((size_t)2 * LC + j) * 64 + b] = av + cbv[0];
}

// ---------------- shared GEMM microtile body (64b x 64d x CK), no atomics ---
__device__ __forceinline__ void gemm_tile(
    const float* __restrict__ Asrc,   // [jc][64] chunk, b-contiguous
    const float* __restrict__ Brow,   // weight base, row stride ldB
    int ldB, int dgb, int j0, int jc,
    float* __restrict__ Pt,           // output tile [64 b][64 d]
    float* lds)
{
    float* ldsC = lds;                // [96][64]  = 6144
    float* ldsW = lds + 6144;         // [64][97]  = 6208
    int tid  = threadIdx.x;
    int lane = tid & 63;
    int w    = tid >> 6;
    int b0   = (lane & 7) << 3;
    int d0   = (lane >> 3) << 3;

    {   // stage A chunk via float4 (fully coalesced)
        const float4* src = (const float4*)Asrc;
        float4* dst = (float4*)ldsC;
        for (int t = tid; t < jc * 16; t += 256) dst[t] = src[t];
    }
    // stage B tile via float2 (row strides even): 64 rows x 48 f2
    for (int idx = tid; idx < 3072; idx += 256) {
        int dd = idx / 48, j2 = idx % 48;
        int dg = dgb + dd;
        float2 v = make_float2(0.f, 0.f);
        if (dg < ND && 2 * j2 < jc)
            v = *(const float2*)(Brow + (size_t)dg * ldB + j0 + 2 * j2);
        ldsW[dd * 97 + 2 * j2]     = v.x;
        ldsW[dd * 97 + 2 * j2 + 1] = v.y;
    }
    __syncthreads();

    float acc[8][8];
#pragma unroll
    for (int i = 0; i < 8; ++i)
#pragma unroll
        for (int jx = 0; jx < 8; ++jx) acc[i][jx] = 0.f;

    int js = (jc * w) >> 2;
    int je = (jc * (w + 1)) >> 2;
    for (int jj = js; jj < je; ++jj) {
        float4 c0 = *(const float4*)(ldsC + jj * 64 + b0);
        float4 c1 = *(const float4*)(ldsC + jj * 64 + b0 + 4);
        float cv[8] = {c0.x, c0.y, c0.z, c0.w, c1.x, c1.y, c1.z, c1.w};
        float wv[8];
#pragma unroll
        for (int r = 0; r < 8; ++r) wv[r] = ldsW[(d0 + r) * 97 + jj];
#pragma unroll
        for (int i = 0; i < 8; ++i)
#pragma unroll
            for (int jx = 0; jx < 8; ++jx)
                acc[i][jx] = fmaf(cv[i], wv[jx], acc[i][jx]);
    }
    __syncthreads();   // done with staged data; reuse LDS for reduce

    // two passes (f4 halves of each lane's d-range); per-wave buf [64][36]
    for (int p = 0; p < 2; ++p) {
        float* red = lds + w * 2304;
#pragma unroll
        for (int i = 0; i < 8; ++i)
            *(float4*)(red + (b0 + i) * 36 + (d0 >> 1)) =
                make_float4(acc[i][4*p], acc[i][4*p+1], acc[i][4*p+2], acc[i][4*p+3]);
        __syncthreads();
        for (int t = tid; t < 512; t += 256) {
            int bb = t >> 3, gg = t & 7;
            int o = bb * 36 + 4 * gg;
            float4 a0 = *(const float4*)(lds + o);
            float4 a1 = *(const float4*)(lds + 2304 + o);
            float4 a2 = *(const float4*)(lds + 4608 + o);
            float4 a3 = *(const float4*)(lds + 6912 + o);
            float4 s;
            s.x = a0.x + a1.x + a2.x + a3.x;
            s.y = a0.y + a1.y + a2.y + a3.y;
            s.z = a0.z + a1.z + a2.z + a3.z;
            s.w = a0.w + a1.w + a2.w + a3.w;
            *(float4*)(Pt + bb * 64 + 8 * gg + 4 * p) = s;
        }
        __syncthreads();
    }
}

// ---------------- K2: QKV GEMM partials -> Pp -------------------------------
__global__ __launch_bounds__(256) void k_lin(
    const float* __restrict__ convT,
    const float* __restrict__ lwq, const float* __restrict__ lwk,
    const float* __restrict__ lwv,
    float* __restrict__ Pp)
{
    __shared__ float lds[12352];
    int dgb   = blockIdx.x * 64;
    int which = blockIdx.y;
    int chunk = blockIdx.z;
    int j0 = chunk * CK;
    int jc = (LC - j0 < CK) ? (LC - j0) : CK;
    const float* lw = (which == 0) ? lwq : ((which == 1) ? lwk : lwv);
    const float* Asrc = convT + ((size_t)which * LC + j0) * 64;
    float* Pt = Pp + (((size_t)chunk * 3 + which) * 16 + blockIdx.x) * 4096;
    gemm_tile(Asrc, lw, LC, dgb, j0, jc, Pt, lds);
}

// ---------------- K3: reduce chunks + bias + ReLU + in_proj -> q, kv --------
// k is pre-scaled by log2e so k_attn can use exp2 directly.
__global__ __launch_bounds__(256) void k_act(
    const float* __restrict__ Pp,
    const float* __restrict__ lbq, const float* __restrict__ lbk,
    const float* __restrict__ lbv,
    const float* __restrict__ ipw, const float* __restrict__ ipb,
    float* __restrict__ q, float* __restrict__ kv)
{
    int i = blockIdx.x * 256 + threadIdx.x;
    int b = blockIdx.y;
    if (i >= ND) return;
    int it = i >> 6, il = i & 63;
    float s0 = 0.f, s1 = 0.f, s2 = 0.f;
    for (int c = 0; c < NCH_LIN; ++c) {
        size_t base = (((size_t)c * 3) * 16 + it) * 4096 + (il | (b << 6));
        s0 += Pp[base];
        s1 += Pp[base + 16 * 4096];
        s2 += Pp[base + 32 * 4096];
    }
    const float LOG2E = 1.4426950408889634f;
    float yq = fmaxf(s0 + lbq[i], 0.f) * ipw[0] + ipb[0];
    float yk = fmaxf(s1 + lbk[i], 0.f) * ipw[1] + ipb[1];
    float yv = fmaxf(s2 + lbv[i], 0.f) * ipw[2] + ipb[2];
    q[(size_t)b * ND + i] = yq;
    kv[(size_t)b * 2048 + 2 * i]     = yk * LOG2E;
    kv[(size_t)b * 2048 + 2 * i + 1] = yv;
}

// ---------------- K4: attention, 4-way wave K-split, writes cfT[i][b] -------
__global__ __launch_bounds__(256) void k_attn(
    const float* __restrict__ q, const float* __restrict__ kv,
    const float* __restrict__ opw, const float* __restrict__ opb,
    float* __restrict__ cfT)
{
    __shared__ float ldsKV[2048];
    __shared__ float sden[256];
    __shared__ float snum[256];
    __shared__ float rmax[4];
    __shared__ float rmin[4];
    int tid = threadIdx.x;
    int b   = blockIdx.y;
    int w   = tid >> 6;           // wave id (uniform)
    int ii  = tid & 63;
    int i   = blockIdx.x * 64 + ii;

    {   // stage kv[b] (8 KB; k pre-scaled by log2e)
        const float4* src = (const float4*)(kv + (size_t)b * 2048);
        float4* dst = (float4*)ldsKV;
        for (int t = tid; t < 512; t += 256) dst[t] = src[t];
    }
    __syncthreads();

    const float2* kv2 = (const float2*)ldsKV;
    float km = -INFINITY, kn = INFINITY;
    for (int idx = tid; idx < ND; idx += 256) {
        float f = kv2[idx].x;
        km = fmaxf(km, f);
        kn = fminf(kn, f);
    }
#pragma unroll
    for (int off = 1; off < 64; off <<= 1) {
        km = fmaxf(km, __shfl_xor(km, off));
        kn = fminf(kn, __shfl_xor(kn, off));
    }
    if (ii == 0) { rmax[w] = km; rmin[w] = kn; }
    __syncthreads();
    km = fmaxf(fmaxf(rmax[0], rmax[1]), fmaxf(rmax[2], rmax[3]));
    kn = fminf(fminf(rmin[0], rmin[1]), fminf(rmin[2], rmin[3]));

    float qi = (i < ND) ? q[(size_t)b * ND + i] : 0.f;
    float m  = (qi >= 0.f) ? qi * km : qi * kn;

    int jb = w * 250;
    float den = 0.f, num = 0.f;
#pragma unroll 2
    for (int jl = 0; jl < 250; ++jl) {
        float2 f = kv2[jb + jl];
        float e  = exp2f(fmaf(qi, f.x, -m));
        den += e;
        num = fmaf(e, f.y, num);
    }
    sden[tid] = den;
    snum[tid] = num;
    __syncthreads();
    if (w == 0 && i < ND) {
        float dt = sden[ii] + sden[64 + ii] + sden[128 + ii] + sden[192 + ii];
        float nt = snum[ii] + snum[64 + ii] + snum[128 + ii] + snum[192 + ii];
        cfT[(size_t)i * 64 + b] = (nt / dt) * opw[0] + opb[0];
    }
}

// ---------------- K5: out GEMM partials -> Op -------------------------------
__global__ __launch_bounds__(256) void k_out(
    const float* __restrict__ cfT, const float* __restrict__ W,
    float* __restrict__ Op)
{
    __shared__ float lds[12352];
    int egb   = blockIdx.x * 64;
    int chunk = blockIdx.y;
    int j0 = chunk * CK;
    int jc = (ND - j0 < CK) ? (ND - j0) : CK;
    const float* Asrc = cfT + (size_t)j0 * 64;
    float* Pt = Op + ((size_t)chunk * 16 + blockIdx.x) * 4096;
    gemm_tile(Asrc, W, ND, egb, j0, jc, Pt, lds);
}

// ---------------- K6: reduce Op chunks + bias -> out ------------------------
__global__ __launch_bounds__(256) void k_fin(
    const float* __restrict__ Op, const float* __restrict__ outb,
    float* __restrict__ out)
{
    int e = blockIdx.x * 256 + threadIdx.x;
    int b = blockIdx.y;
    if (e >= ND) return;
    float s = outb[e];
    size_t cell = ((size_t)(e >> 6)) * 4096 + (b << 6) + (e & 63);
    for (int c = 0; c < NCH_OUT; ++c)
        s += Op[(size_t)c * 16 * 4096 + cell];
    out[(size_t)b * ND + e] = s;
}

extern "C" void kernel_launch(void* const* d_in, const int* in_sizes, int n_in,
                              void* d_out, int out_size, void* d_ws, size_t ws_size,
                              hipStream_t stream)
{
    const float* x    = (const float*)d_in[0];
    const float* g    = (const float*)d_in[1];
    const float* be   = (const float*)d_in[2];
    const float* mu   = (const float*)d_in[3];
    const float* va   = (const float*)d_in[4];
    const float* cwq  = (const float*)d_in[5];
    const float* cbq  = (const float*)d_in[6];
    const float* lwq  = (const float*)d_in[7];
    const float* lbq  = (const float*)d_in[8];
    const float* cwk  = (const float*)d_in[9];
    const float* cbk  = (const float*)d_in[10];
    const float* lwk  = (const float*)d_in[11];
    const float* lbk  = (const float*)d_in[12];
    const float* cwv  = (const float*)d_in[13];
    const float* cbv  = (const float*)d_in[14];
    const float* lwv  = (const float*)d_in[15];
    const float* lbv  = (const float*)d_in[16];
    const float* ipw  = (const float*)d_in[17];
    const float* ipb  = (const float*)d_in[18];
    const float* opw  = (const float*)d_in[19];
    const float* opb  = (const float*)d_in[20];
    const float* W    = (const float*)d_in[21];
    const float* outb = (const float*)d_in[22];

    float* ws    = (float*)d_ws;
    float* convT = ws + OFF_CONVT;
    float* Pp    = ws + OFF_PP;
    float* q     = ws + OFF_Q;
    float* kv    = ws + OFF_KV;
    float* cfT   = ws + OFF_CF;
    float* Op    = ws + OFF_OP;
    float* out   = (float*)d_out;

    k_bnconv<<<dim3(4, 64), 256, 0, stream>>>(x, g, be, mu, va,
                                              cwq, cbq, cwk, cbk, cwv, cbv, convT);
    k_lin  <<<dim3(16, 3, NCH_LIN), 256, 0, stream>>>(convT, lwq, lwk, lwv, Pp);
    k_act  <<<dim3(4, 64), 256, 0, stream>>>(Pp, lbq, lbk, lbv, ipw, ipb, q, kv);
    k_attn <<<dim3(16, 64), 256, 0, stream>>>(q, kv, opw, opb, cfT);
    k_out  <<<dim3(16, NCH_OUT), 256, 0, stream>>>(cfT, W, Op);
    k_fin  <<<dim3(4, 64), 256, 0, stream>>>(Op, outb, out);
}